// Round 4
// baseline (492.160 us; speedup 1.0000x reference)
//
#include <hip/hip_runtime.h>
#include <hip/hip_bf16.h>

#define N 224
#define TS 32
#define NT 7          // N / TS
#define PITCH 33      // 33 % 32 == 1 -> ~2-way max bank aliasing (free) on all patterns

// Group element g maps output pixel (i,j) -> source pixel m_g(i,j):
//   m0:(i,j) m1:(j,ri) m2:(ri,rj) m3:(rj,i) m4:(i,rj) m5:(j,i) m6:(ri,j) m7:(rj,ri)
// COMP[g][h] = index of m_g ∘ m_h. Verified (passed rounds 1-3).
// Block structure: COMP[g][h] < 4  <=>  (g<4) == (h<4).
constexpr int COMP[8][8] = {
    {0,1,2,3,4,5,6,7},
    {1,2,3,0,7,4,5,6},
    {2,3,0,1,6,7,4,5},
    {3,0,1,2,5,6,7,4},
    {4,5,6,7,0,1,2,3},
    {5,6,7,4,3,0,1,2},
    {6,7,4,5,2,3,0,1},
    {7,4,5,6,1,2,3,0},
};
// CAN[class][u] = canonical LDS slot (<4) of tile tau_u for degenerate orbits.
constexpr int CAN[4][8] = {
    {0,1,2,3,4,5,6,7},   // class 0: generic (handled two-phase, slot = COMP&3)
    {0,1,2,3,0,3,2,1},   // class 1: axis J==3 (4 unique tiles)
    {0,1,2,3,1,0,3,2},   // class 2: diagonal I==J (4 unique tiles)
    {0,0,0,0,0,0,0,0},   // class 3: center (1 tile)
};

// intra-tile read index for group g (g is compile-time after unroll -> folds)
__device__ __forceinline__ int gidx(int g, int ti, int tj, int rti, int rtj) {
    switch (g) {
        case 0: return ti  * PITCH + tj;
        case 1: return tj  * PITCH + rti;
        case 2: return rti * PITCH + rtj;
        case 3: return rtj * PITCH + ti;
        case 4: return ti  * PITCH + rtj;
        case 5: return tj  * PITCH + ti;
        default: break;
    }
    return (g == 6) ? (rti * PITCH + tj) : (rtj * PITCH + rti);
}

// Generic-orbit accumulation for one phase. P=0: slots hold tiles 0-3,
// P=1: slots hold tiles 4-7. Exactly 4 of 8 groups contribute per (h, P).
template<int P>
__device__ __forceinline__ void gen_phase(float (&acc)[8][4], const float* c,
        const float (*lds)[TS * PITCH], int row, int cg)
{
    const int ti = row, rti = TS - 1 - row;
    #pragma unroll
    for (int h = 0; h < 8; ++h) {
        #pragma unroll
        for (int q = 0; q < 4; ++q) {
            const int tj = cg + q, rtj = TS - 1 - tj;
            float s = acc[h][q];
            #pragma unroll
            for (int g = 0; g < 8; ++g) {
                if ((COMP[g][h] >> 2) == P) {       // compile-time condition
                    s += c[g] * lds[COMP[g][h] & 3][gidx(g, ti, tj, rti, rtj)];
                }
            }
            acc[h][q] = s;
        }
    }
}

__global__ __launch_bounds__(256, 5) void popmi_kernel(
        const float* __restrict__ x, const float* __restrict__ theta,
        float* __restrict__ out)
{
    __shared__ float lds[4][TS * PITCH];   // 16,896 B -> up to 9 blocks/CU by LDS

    // coefficients from theta (8 floats), recomputed per thread:
    // coef[g] = (BETA/w_sum)*softmax(theta)[g]; coef[0] += 1-BETA
    float th[8];
    #pragma unroll
    for (int i = 0; i < 8; ++i) th[i] = theta[i];
    float m = th[0];
    #pragma unroll
    for (int i = 1; i < 8; ++i) m = fmaxf(m, th[i]);
    float e[8], S = 0.f;
    #pragma unroll
    for (int i = 0; i < 8; ++i) { e[i] = expf(th[i] - m); S += e[i]; }
    float w[8], ws = 0.f;
    #pragma unroll
    for (int i = 0; i < 8; ++i) { w[i] = e[i] / S; ws += w[i]; }
    const float s0 = 0.5f / fmaxf(ws, 1e-12f);
    float c[8];
    #pragma unroll
    for (int i = 0; i < 8; ++i) c[i] = s0 * w[i];
    c[0] += 0.5f;

    const int bid = blockIdx.x;
    const int p   = bid / 10;           // plane
    const int o   = bid - p * 10;       // orbit id 0..9

    // orbit rep (I,J), 3 bits/entry: OI={0,0,1,0,1,2,0,1,2,3} OJ={1,2,2,3,3,3,0,1,2,3}
    const int I = (0x1A211040u >> (3 * o)) & 7;
    const int J = (0x1A21B691u >> (3 * o)) & 7;
    const int rI = NT - 1 - I, rJ = NT - 1 - J;

    const int TI[8] = { I,  J, rI, rJ,  I,  J, rI, rJ };
    const int TJ[8] = { J, rI, rJ,  I, rJ,  I,  J, rI };

    const float* plane  = x   + (size_t)p * (N * N);
    float*       oplane = out + (size_t)p * (N * N);

    const int tid = threadIdx.x;
    const int row = tid >> 3;           // 0..31
    const int cg  = (tid & 7) << 2;     // 0,4,...,28
    const int ti  = row, rti = TS - 1 - row;

    if (o < 3) {
        // ---- generic orbit: 8 tiles, two phases over 4 LDS slots ----
        #pragma unroll
        for (int u = 0; u < 4; ++u) {
            const float4 v = *reinterpret_cast<const float4*>(
                plane + (size_t)(TI[u] * TS + row) * N + TJ[u] * TS + cg);
            float* dst = &lds[u][row * PITCH + cg];
            dst[0] = v.x; dst[1] = v.y; dst[2] = v.z; dst[3] = v.w;
        }
        __syncthreads();

        // prefetch phase-B tiles while phase-A compute runs
        float4 vb[4];
        #pragma unroll
        for (int u = 0; u < 4; ++u) {
            vb[u] = *reinterpret_cast<const float4*>(
                plane + (size_t)(TI[u + 4] * TS + row) * N + TJ[u + 4] * TS + cg);
        }

        float acc[8][4] = {{0.f}};
        gen_phase<0>(acc, c, lds, row, cg);
        __syncthreads();

        #pragma unroll
        for (int u = 0; u < 4; ++u) {
            float* dst = &lds[u][row * PITCH + cg];
            dst[0] = vb[u].x; dst[1] = vb[u].y; dst[2] = vb[u].z; dst[3] = vb[u].w;
        }
        __syncthreads();

        gen_phase<1>(acc, c, lds, row, cg);

        #pragma unroll
        for (int h = 0; h < 8; ++h) {
            *reinterpret_cast<float4*>(
                oplane + (size_t)(TI[h] * TS + row) * N + TJ[h] * TS + cg)
                = make_float4(acc[h][0], acc[h][1], acc[h][2], acc[h][3]);
        }
    } else {
        // ---- degenerate orbits: <=4 unique tiles, single phase ----
        const int cls = (o < 6) ? 1 : (o < 9) ? 2 : 3;
        const int nu  = (cls == 3) ? 1 : 4;
        const int nh  = (cls == 3) ? 1 : 4;

        for (int u = 0; u < nu; ++u) {      // nu is wave-uniform
            const float4 v = *reinterpret_cast<const float4*>(
                plane + (size_t)(TI[u] * TS + row) * N + TJ[u] * TS + cg);
            float* dst = &lds[u][row * PITCH + cg];
            dst[0] = v.x; dst[1] = v.y; dst[2] = v.z; dst[3] = v.w;
        }
        __syncthreads();

        #pragma unroll
        for (int h = 0; h < 4; ++h) {
            if (h < nh) {                   // wave-uniform guard
                float res[4];
                #pragma unroll
                for (int q = 0; q < 4; ++q) {
                    const int tj = cg + q, rtj = TS - 1 - tj;
                    float acc0 = 0.f;
                    #pragma unroll
                    for (int g = 0; g < 8; ++g) {
                        // slot: cls==1 -> CAN[1], cls==2 -> CAN[2], cls==3 -> 0
                        const int slot1 = CAN[1][COMP[g][h]];
                        const int slot2 = CAN[2][COMP[g][h]];
                        const int slot  = (cls == 1) ? slot1 : (cls == 2) ? slot2 : 0;
                        acc0 += c[g] * lds[slot][gidx(g, ti, tj, rti, rtj)];
                    }
                    res[q] = acc0;
                }
                *reinterpret_cast<float4*>(
                    oplane + (size_t)(TI[h] * TS + row) * N + TJ[h] * TS + cg)
                    = make_float4(res[0], res[1], res[2], res[3]);
            }
        }
    }
}

extern "C" void kernel_launch(void* const* d_in, const int* in_sizes, int n_in,
                              void* d_out, int out_size, void* d_ws, size_t ws_size,
                              hipStream_t stream) {
    const float* x     = (const float*)d_in[0];
    const float* theta = (const float*)d_in[1];
    float* out = (float*)d_out;

    const int planes = in_sizes[0] / (N * N);   // 16*192 = 3072
    popmi_kernel<<<planes * 10, 256, 0, stream>>>(x, theta, out);
}